// Round 13
// baseline (1402.964 us; speedup 1.0000x reference)
//
#include <hip/hip_runtime.h>
#include <hip/hip_cooperative_groups.h>
#include <hip/hip_bf16.h>
#include <math.h>

namespace cg = cooperative_groups;

typedef __hip_bfloat16 bf16;
typedef __bf16 v8bf __attribute__((ext_vector_type(8)));
typedef float v4f __attribute__((ext_vector_type(4)));

#define BN_SCALE 0.9999950000374997f
#define NPTS 1024
#define NB 4
#define TW 40  // LDS tile row stride in bf16 (80B: 2-way bank alias only = free)

__device__ __forceinline__ float b2f(bf16 v) { return __bfloat162float(v); }
__device__ __forceinline__ bf16 f2b(float v) { return __float2bfloat16(v); }
__device__ __forceinline__ float ldw(const void* p, size_t i, int isf) {
    return isf ? ((const float*)p)[i] : b2f(((const bf16*)p)[i]);
}
__device__ __forceinline__ unsigned ordf(float f) {
    unsigned u = __float_as_uint(f);
    return (u & 0x80000000u) ? ~u : (u | 0x80000000u);
}
__device__ __forceinline__ float iordf(unsigned u) {
    return (u & 0x80000000u) ? __uint_as_float(u ^ 0x80000000u) : __uint_as_float(~u);
}

__device__ __forceinline__ void fillA(bf16* dst, const bf16* srcRowBase, int ld) {
    int t = threadIdx.x; int r = t >> 2; int kq = (t & 3) << 3;
    *(float4*)(dst + r * TW + kq) = *(const float4*)(srcRowBase + (size_t)r * ld + kq);
}
__device__ __forceinline__ v8bf ldfrag(const bf16* tile, int sub, int l) {
    return *(const v8bf*)(tile + (size_t)(sub * 16 + (l & 15)) * TW + ((l >> 4) << 3));
}

// workspace byte offsets (round-12 layout)
#define OFF_XCHI  0
#define OFF_XCLO  7864320
#define OFF_XPADH 15728640
#define OFF_XPADL 15990784
#define OFF_D     16252928
#define OFF_P     33030144
#define OFF_WHI   49807360
#define OFF_WLO   51486720
#define OFF_IDX   53166080
#define OFF_POOL  53493760
#define OFF_SQ    53501952
#define OFF_FLAG  53518336

__global__ __launch_bounds__(256, 4) void k_net(
    const void* x,
    const void* W1, const void* g1, const void* b1,
    const void* W2, const void* g2, const void* b2,
    const void* W3, const void* g3, const void* b3,
    const void* W4, const void* g4, const void* b4,
    const void* W5, const void* g5, const void* b5,
    const void* We, char* ws, void* out)
{
    cg::grid_group gg = cg::this_grid();

    bf16*     xc_hi   = (bf16*)(ws + OFF_XCHI);
    bf16*     xc_lo   = (bf16*)(ws + OFF_XCLO);
    bf16*     xpadh   = (bf16*)(ws + OFF_XPADH);
    bf16*     xpadl   = (bf16*)(ws + OFF_XPADL);
    float*    Dbuf    = (float*)(ws + OFF_D);
    float*    Pbuf    = (float*)(ws + OFF_P);
    bf16*     Whi     = (bf16*)(ws + OFF_WHI);
    bf16*     Wlo     = (bf16*)(ws + OFF_WLO);
    int*      idxb    = (int*)(ws + OFF_IDX);
    unsigned* pooledU = (unsigned*)(ws + OFF_POOL);
    float*    sq      = (float*)(ws + OFF_SQ);
    int*      flagp   = (int*)(ws + OFF_FLAG);

    int bid = blockIdx.x, tid = threadIdx.x;
    int localCount = gridDim.x >> 2;                  // blocks per batch z
    int z = (bid >> 1) & 3;                           // XCD-pinned batch
    int local = ((bid >> 3) << 1) | (bid & 1);        // 0..localCount-1
    int wv = tid >> 6, l64 = tid & 63;
    int quad = l64 >> 4, col = l64 & 15;

    __shared__ alignas(16) bf16 Ah[64 * TW], Al[64 * TW], Bh[64 * TW], Bl[64 * TW];
    __shared__ int ids[20];
    __shared__ float redS[8];
    __shared__ float red2[4][4][16];
    __shared__ float pS[512];
    __shared__ int cnt[256];

    // ---------------- stage 0: dtype probe + pooled init (block 0) ----------------
    if (bid == 0) {
        const unsigned short* u = (const unsigned short*)x;
        int c = 0;
        for (int i = tid; i < 8192; i += 256) {
            unsigned short v = u[i];
            int e = (v >> 7) & 0xFF;
            int m = v & 0x7F;
            if (e == 0xFF || e >= 141 || (e == 0 && m != 0)) c++;
        }
        cnt[tid] = c;
        for (int i = tid; i < 2048; i += 256) pooledU[i] = 0u;
        __syncthreads();
        for (int off = 128; off > 0; off >>= 1) {
            if (tid < off) cnt[tid] += cnt[tid + off];
            __syncthreads();
        }
        if (tid == 0) *flagp = (cnt[0] > 200) ? 1 : 0;
    }
    gg.sync();
    int isf = *flagp;

    // ---------------- stage 1: prep (weight hi/lo split + x pad + sq) ----------------
    for (int idx = bid * 256 + tid; idx < 843776; idx += gridDim.x * 256) {
        if (idx < 839680) {
            const void* src; int C, O, Kp, two, loc;
            if (idx < 4096)        { src = W1; C = 3;   O = 64;  Kp = 32;  two = 1; loc = idx; }
            else if (idx < 20480)  { src = W2; C = 64;  O = 128; Kp = 64;  two = 1; loc = idx - 4096; }
            else if (idx < 86016)  { src = W3; C = 128; O = 256; Kp = 128; two = 1; loc = idx - 20480; }
            else if (idx < 348160) { src = W4; C = 256; O = 512; Kp = 256; two = 1; loc = idx - 86016; }
            else                   { src = W5; C = 960; O = 512; Kp = 960; two = 0; loc = idx - 348160; }
            int r = loc / Kp, c = loc % Kp;
            float wvv = 0.f;
            if (c < C) {
                size_t off;
                if (two) off = (r < O) ? (size_t)r * 2 * C + c : (size_t)(r - O) * 2 * C + C + c;
                else     off = (size_t)r * C + c;
                wvv = ldw(src, off, isf);
            }
            bf16 h = f2b(wvv);
            Whi[idx] = h;
            Wlo[idx] = f2b(wvv - b2f(h));
        } else {
            int p = idx - 839680;
            int zz = p >> 10, n = p & 1023;
            bf16* ph = xpadh + (size_t)zz * NPTS * 32;
            bf16* pl = xpadl + (size_t)zz * NPTS * 32;
            float s = 0.f;
            for (int c = 0; c < 32; c++) {
                float v = (c < 3) ? ldw(x, (size_t)zz * NPTS * 3 + n * 3 + c, isf) : 0.f;
                bf16 h = f2b(v);
                ph[n * 32 + c] = h;
                pl[n * 32 + c] = f2b(v - b2f(h));
                s += v * v;
            }
            sq[zz * NPTS + n] = s;
        }
    }
    gg.sync();

    // ---------------- layers ----------------
    const int Kpads[4] = { 32, 64, 128, 256 };
    const int Osz[4]   = { 64, 128, 256, 512 };
    const int WoffL[4] = { 0, 4096, 20480, 86016 };
    const int cIn[4]   = { 0, 0, 64, 192 };
    const int cOut[4]  = { 0, 64, 192, 448 };

#pragma unroll 1
    for (int l = 0; l < 4; l++) {
        int Kpad = Kpads[l], O = Osz[l];
        int nTilesO = (2 * O) >> 6;
        int nBlk = 136 + 16 * nTilesO;
        int ld = (l == 0) ? 32 : 960;
        size_t xstr = (l == 0) ? (size_t)NPTS * 32 : (size_t)NPTS * 960;
        const bf16* Xh = ((l == 0) ? xpadh : (xc_hi + cIn[l])) + (size_t)z * xstr;
        const bf16* Xl = ((l == 0) ? xpadl : (xc_lo + cIn[l])) + (size_t)z * xstr;
        const bf16* Whl = Whi + WoffL[l];
        const bf16* Wll = Wlo + WoffL[l];
        const void* gcur = (l == 0) ? g1 : (l == 1) ? g2 : (l == 2) ? g3 : g4;
        const void* bcur = (l == 0) ? b1 : (l == 1) ? b2 : (l == 2) ? b3 : b4;
        int N2 = 2 * O;

        // ---- stage A: dist (upper-tri tiles) + st ----
        for (int wi = local; wi < nBlk; wi += localCount) {
            v4f zero = {0.f, 0.f, 0.f, 0.f};
            v4f acc[4] = {zero, zero, zero, zero};
            if (wi < 136) {
                int bx = 0;
                while ((((bx + 1) * (bx + 2)) >> 1) <= wi) bx++;
                int by = wi - ((bx * (bx + 1)) >> 1);
                const float* sqz = sq + z * NPTS;
                float* D = Dbuf + (size_t)z * NPTS * NPTS;
                int n0 = by * 64, m0 = bx * 64;
                for (int k0 = 0; k0 < Kpad; k0 += 32) {
                    __syncthreads();
                    fillA(Ah, Xh + (size_t)n0 * ld + k0, ld);
                    fillA(Bh, Xh + (size_t)m0 * ld + k0, ld);
                    fillA(Al, Xl + (size_t)n0 * ld + k0, ld);
                    fillA(Bl, Xl + (size_t)m0 * ld + k0, ld);
                    __syncthreads();
                    v8bf ah = ldfrag(Ah, wv, l64);
                    v8bf al = ldfrag(Al, wv, l64);
#pragma unroll
                    for (int nt = 0; nt < 4; nt++) {
                        v8bf bh = ldfrag(Bh, nt, l64);
                        v8bf bl = ldfrag(Bl, nt, l64);
                        acc[nt] = __builtin_amdgcn_mfma_f32_16x16x32_bf16(ah, bh, acc[nt], 0, 0, 0);
                        acc[nt] = __builtin_amdgcn_mfma_f32_16x16x32_bf16(ah, bl, acc[nt], 0, 0, 0);
                        acc[nt] = __builtin_amdgcn_mfma_f32_16x16x32_bf16(al, bh, acc[nt], 0, 0, 0);
                    }
                }
                int nb = n0 + 16 * wv + quad * 4;
                float sm[4];
#pragma unroll
                for (int nt = 0; nt < 4; nt++) sm[nt] = sqz[m0 + nt * 16 + col];
#pragma unroll
                for (int r = 0; r < 4; r++) {
                    float sn = sqz[nb + r];
#pragma unroll
                    for (int nt = 0; nt < 4; nt++) {
                        float d = 2.f * acc[nt][r] - sn - sm[nt];
                        int m = m0 + nt * 16 + col;
                        D[(size_t)(nb + r) * NPTS + m] = d;
                        if (bx != by) D[(size_t)m * NPTS + nb + r] = d;
                    }
                }
            } else {
                int s = wi - 136;
                int n0 = (s % nTilesO) * 64;
                int m0 = (s / nTilesO) * 64;
                float* P = Pbuf + (size_t)z * NPTS * N2;
                for (int k0 = 0; k0 < Kpad; k0 += 32) {
                    __syncthreads();
                    fillA(Ah, Xh + (size_t)m0 * ld + k0, ld);
                    fillA(Al, Xl + (size_t)m0 * ld + k0, ld);
                    fillA(Bh, Whl + (size_t)n0 * Kpad + k0, Kpad);
                    if (isf) fillA(Bl, Wll + (size_t)n0 * Kpad + k0, Kpad);
                    __syncthreads();
                    v8bf ah = ldfrag(Ah, wv, l64);
                    v8bf al = ldfrag(Al, wv, l64);
#pragma unroll
                    for (int nt = 0; nt < 4; nt++) {
                        v8bf bh = ldfrag(Bh, nt, l64);
                        acc[nt] = __builtin_amdgcn_mfma_f32_16x16x32_bf16(ah, bh, acc[nt], 0, 0, 0);
                        acc[nt] = __builtin_amdgcn_mfma_f32_16x16x32_bf16(al, bh, acc[nt], 0, 0, 0);
                        if (isf) {
                            v8bf bl = ldfrag(Bl, nt, l64);
                            acc[nt] = __builtin_amdgcn_mfma_f32_16x16x32_bf16(ah, bl, acc[nt], 0, 0, 0);
                        }
                    }
                }
                int rb = m0 + 16 * wv + quad * 4;
#pragma unroll
                for (int r = 0; r < 4; r++)
#pragma unroll
                    for (int nt = 0; nt < 4; nt++)
                        P[(size_t)(rb + r) * N2 + n0 + nt * 16 + col] = acc[nt][r];
            }
        }
        gg.sync();

        // ---- stage B: top-20 (register-resident, wave per row) ----
        for (int row = local * 4 + wv; row < NPTS; row += localCount * 4) {
            const float* Dr = Dbuf + (size_t)z * NPTS * NPTS + (size_t)row * NPTS;
            float v[16];
#pragma unroll
            for (int j = 0; j < 16; j++) v[j] = Dr[j * 64 + l64];
            for (int s = 0; s < 20; s++) {
                float bv = v[0]; int bj = 0;
#pragma unroll
                for (int j = 1; j < 16; j++)
                    if (v[j] > bv) { bv = v[j]; bj = j; }   // ascending keeps min j on tie
                int bi = bj * 64 + l64;
#pragma unroll
                for (int off = 1; off < 64; off <<= 1) {
                    float ov = __shfl_xor(bv, off);
                    int   oi = __shfl_xor(bi, off);
                    if (ov > bv || (ov == bv && oi < bi)) { bv = ov; bi = oi; }
                }
                if (l64 == 0) idxb[(z * NPTS + row) * 20 + s] = bi;
                if ((bi & 63) == l64) {
                    int ej = bi >> 6;
#pragma unroll
                    for (int j = 0; j < 16; j++)
                        if (j == ej) v[j] = -__builtin_inff();
                }
            }
        }
        gg.sync();

        // ---- stage C: gather + affine + lrelu + max over k ----
        {
            const float* P = Pbuf + (size_t)z * NPTS * N2;
            int writeSq = (l < 3);
            bf16* xh = xc_hi + cOut[l] + (size_t)z * NPTS * 960;
            bf16* xl2 = xc_lo + cOut[l] + (size_t)z * NPTS * 960;
            for (int n = local; n < NPTS; n += localCount) {
                if (tid < 20) ids[tid] = idxb[(z * NPTS + n) * 20 + tid];
                __syncthreads();
                float ssum = 0.f;
                for (int o = tid; o < O; o += 256) {
                    float tv = P[(size_t)n * N2 + O + o] - P[(size_t)n * N2 + o];
                    float scl = ldw(gcur, o, isf) * BN_SCALE;
                    float bb = ldw(bcur, o, isf);
                    float acc = -__builtin_inff();
                    for (int j = 0; j < 20; j++) {
                        int m = ids[j];
                        float v = P[(size_t)m * N2 + o] + tv;
                        float z2 = v * scl + bb;
                        z2 = z2 > 0.f ? z2 : 0.2f * z2;
                        acc = fmaxf(acc, z2);
                    }
                    bf16 hi = f2b(acc);
                    bf16 lo = f2b(acc - b2f(hi));
                    xh[(size_t)n * 960 + o] = hi;
                    xl2[(size_t)n * 960 + o] = lo;
                    if (writeSq) {
                        float xv = b2f(hi) + b2f(lo);
                        ssum += xv * xv;
                    }
                }
                if (writeSq) {
#pragma unroll
                    for (int off = 32; off > 0; off >>= 1) ssum += __shfl_down(ssum, off);
                    if (l64 == 0) redS[wv] = ssum;
                    __syncthreads();
                    if (tid == 0) {
                        float tot = ((redS[0] + redS[1]) + redS[2]) + redS[3];
                        sq[z * NPTS + n] = tot;
                    }
                }
                __syncthreads();
            }
        }
        gg.sync();
    }

    // ---------------- conv5 + fused affine/lrelu/max-pool ----------------
    {
        const bf16* Xh = xc_hi + (size_t)z * NPTS * 960;
        const bf16* Xl = xc_lo + (size_t)z * NPTS * 960;
        const bf16* W5h = Whi + 348160;
        const bf16* W5l = Wlo + 348160;
        for (int wi = local; wi < 128; wi += localCount) {
            int o0 = (wi & 7) * 64, m0 = (wi >> 3) * 64;
            v4f zero = {0.f, 0.f, 0.f, 0.f};
            v4f acc[4] = {zero, zero, zero, zero};
            for (int k0 = 0; k0 < 960; k0 += 32) {
                __syncthreads();
                fillA(Ah, Xh + (size_t)m0 * 960 + k0, 960);
                fillA(Al, Xl + (size_t)m0 * 960 + k0, 960);
                fillA(Bh, W5h + (size_t)o0 * 960 + k0, 960);
                if (isf) fillA(Bl, W5l + (size_t)o0 * 960 + k0, 960);
                __syncthreads();
                v8bf ah = ldfrag(Ah, wv, l64);
                v8bf al = ldfrag(Al, wv, l64);
#pragma unroll
                for (int nt = 0; nt < 4; nt++) {
                    v8bf bh = ldfrag(Bh, nt, l64);
                    acc[nt] = __builtin_amdgcn_mfma_f32_16x16x32_bf16(ah, bh, acc[nt], 0, 0, 0);
                    acc[nt] = __builtin_amdgcn_mfma_f32_16x16x32_bf16(al, bh, acc[nt], 0, 0, 0);
                    if (isf) {
                        v8bf bl = ldfrag(Bl, nt, l64);
                        acc[nt] = __builtin_amdgcn_mfma_f32_16x16x32_bf16(ah, bl, acc[nt], 0, 0, 0);
                    }
                }
            }
#pragma unroll
            for (int nt = 0; nt < 4; nt++) {
                int o = o0 + nt * 16 + col;
                float scl = ldw(g5, o, isf) * BN_SCALE;
                float bi = ldw(b5, o, isf);
                float ym = -__builtin_inff();
#pragma unroll
                for (int r = 0; r < 4; r++) {
                    float v = acc[nt][r] * scl + bi;
                    v = v > 0.f ? v : 0.2f * v;
                    ym = fmaxf(ym, v);
                }
                ym = fmaxf(ym, __shfl_down(ym, 32));
                ym = fmaxf(ym, __shfl_down(ym, 16));
                if (quad == 0) red2[wv][nt][col] = ym;
            }
            __syncthreads();
            if (tid < 64) {
                int nt = tid >> 4, c = tid & 15;
                float m = fmaxf(fmaxf(red2[0][nt][c], red2[1][nt][c]),
                                fmaxf(red2[2][nt][c], red2[3][nt][c]));
                atomicMax(&pooledU[z * 512 + o0 + nt * 16 + c], ordf(m));
            }
            __syncthreads();
        }
    }
    gg.sync();

    // ---------------- final linear ----------------
    if (bid < 16) {
        int b = bid >> 2, fb = bid & 3;
        for (int i = tid; i < 512; i += 256) pS[i] = iordf(pooledU[b * 512 + i]);
        __syncthreads();
        for (int it = 0; it < 16; it++) {
            int f = fb * 64 + wv * 16 + it;
            float s = 0.f;
            size_t basei = (size_t)f * 512 + l64 * 8;
#pragma unroll
            for (int j = 0; j < 8; j++) s += pS[l64 * 8 + j] * ldw(We, basei + j, isf);
#pragma unroll
            for (int off = 32; off > 0; off >>= 1) s += __shfl_down(s, off);
            if (l64 == 0) {
                if (isf) ((float*)out)[b * 256 + f] = s;
                else     ((bf16*)out)[b * 256 + f] = f2b(s);
            }
        }
    }
}

extern "C" void kernel_launch(void* const* d_in, const int* in_sizes, int n_in,
                              void* d_out, int out_size, void* d_ws, size_t ws_size,
                              hipStream_t stream) {
    const void* x  = d_in[0];
    const void* W1 = d_in[1];  const void* g1 = d_in[2];  const void* b1 = d_in[3];
    const void* W2 = d_in[4];  const void* g2 = d_in[5];  const void* b2 = d_in[6];
    const void* W3 = d_in[7];  const void* g3 = d_in[8];  const void* b3 = d_in[9];
    const void* W4 = d_in[10]; const void* g4 = d_in[11]; const void* b4 = d_in[12];
    const void* W5 = d_in[13]; const void* g5 = d_in[14]; const void* b5 = d_in[15];
    const void* We = d_in[16];
    char* ws = (char*)d_ws;
    void* out = d_out;

    int maxb = 0;
    if (hipOccupancyMaxActiveBlocksPerMultiprocessor(&maxb, (const void*)k_net, 256, 0)
            != hipSuccess || maxb <= 0)
        maxb = 4;
    int nblk = maxb * 256;           // 256 CUs
    if (nblk > 1024) nblk = 1024;
    nblk &= ~7;                      // decode needs multiple of 8
    if (nblk < 16) nblk = 16;

    void* args[] = { &x, &W1, &g1, &b1, &W2, &g2, &b2, &W3, &g3, &b3,
                     &W4, &g4, &b4, &W5, &g5, &b5, &We, &ws, &out };
    hipLaunchCooperativeKernel((const void*)k_net, dim3(nblk), dim3(256), args, 0, stream);
}

// Round 14
// 347.709 us; speedup vs baseline: 4.0349x; 4.0349x over previous
//
#include <hip/hip_runtime.h>
#include <hip/hip_bf16.h>
#include <math.h>

typedef __hip_bfloat16 bf16;
typedef __bf16 v8bf __attribute__((ext_vector_type(8)));
typedef float v4f __attribute__((ext_vector_type(4)));

#define BN_SCALE 0.9999950000374997f
#define NPTS 1024
#define NB 4
#define TW 40  // LDS tile row stride in bf16 (80B: 2-way bank alias only = free)

__device__ __forceinline__ float b2f(bf16 v) { return __bfloat162float(v); }
__device__ __forceinline__ bf16 f2b(float v) { return __float2bfloat16(v); }
__device__ __forceinline__ float ldw(const void* p, size_t i, int isf) {
    return isf ? ((const float*)p)[i] : b2f(((const bf16*)p)[i]);
}
__device__ __forceinline__ unsigned ordf(float f) {
    unsigned u = __float_as_uint(f);
    return (u & 0x80000000u) ? ~u : (u | 0x80000000u);
}
__device__ __forceinline__ float iordf(unsigned u) {
    return (u & 0x80000000u) ? __uint_as_float(u ^ 0x80000000u) : __uint_as_float(~u);
}

// ---------------- dtype probe (fp32=1 / bf16=0) + pooled init ----------------
__global__ void k_probe(const void* xraw, int* flag, unsigned* pooledU) {
    __shared__ int cnt[256];
    const unsigned short* u = (const unsigned short*)xraw;
    int t = threadIdx.x, c = 0;
    for (int i = t; i < 8192; i += 256) {
        unsigned short v = u[i];
        int e = (v >> 7) & 0xFF;
        int m = v & 0x7F;
        if (e == 0xFF || e >= 141 || (e == 0 && m != 0)) c++;
    }
    cnt[t] = c;
    for (int i = t; i < 2048; i += 256) pooledU[i] = 0u;  // 0 < ordf(any finite)
    __syncthreads();
    for (int off = 128; off > 0; off >>= 1) {
        if (t < off) cnt[t] += cnt[t + off];
        __syncthreads();
    }
    if (t == 0) *flag = (cnt[0] > 200) ? 1 : 0;
}

// ---------------- fused prep: all weight splits + x padding + sq, one launch ----------------
__global__ void k_prep(const void* __restrict__ W1, const void* __restrict__ W2,
                       const void* __restrict__ W3, const void* __restrict__ W4,
                       const void* __restrict__ W5, const void* __restrict__ x,
                       bf16* __restrict__ Whi, bf16* __restrict__ Wlo,
                       bf16* __restrict__ xph, bf16* __restrict__ xpl, float* __restrict__ sq,
                       const int* __restrict__ flag) {
    int isf = *flag;
    int idx = blockIdx.x * 256 + threadIdx.x;
    if (idx < 839680) {
        const void* src; int C, O, Kpad, two, local;
        if (idx < 4096)        { src = W1; C = 3;   O = 64;  Kpad = 32;  two = 1; local = idx; }
        else if (idx < 20480)  { src = W2; C = 64;  O = 128; Kpad = 64;  two = 1; local = idx - 4096; }
        else if (idx < 86016)  { src = W3; C = 128; O = 256; Kpad = 128; two = 1; local = idx - 20480; }
        else if (idx < 348160) { src = W4; C = 256; O = 512; Kpad = 256; two = 1; local = idx - 86016; }
        else                   { src = W5; C = 960; O = 512; Kpad = 960; two = 0; local = idx - 348160; }
        int r = local / Kpad, c = local % Kpad;
        float wv = 0.f;
        if (c < C) {
            size_t off;
            if (two) off = (r < O) ? (size_t)r * 2 * C + c : (size_t)(r - O) * 2 * C + C + c;
            else     off = (size_t)r * C + c;
            wv = ldw(src, off, isf);
        }
        bf16 h = f2b(wv);
        Whi[idx] = h;
        Wlo[idx] = f2b(wv - b2f(h));
    } else if (idx < 843776) {
        int p = idx - 839680;       // point index: z*1024 + n
        int z = p >> 10, n = p & 1023;
        bf16* ph = xph + (size_t)z * NPTS * 32;
        bf16* pl = xpl + (size_t)z * NPTS * 32;
        float s = 0.f;
        for (int c = 0; c < 32; c++) {
            float v = (c < 3) ? ldw(x, (size_t)z * NPTS * 3 + n * 3 + c, isf) : 0.f;
            bf16 h = f2b(v);
            ph[n * 32 + c] = h;
            pl[n * 32 + c] = f2b(v - b2f(h));
            s += v * v;
        }
        sq[z * NPTS + n] = s;
    }
}

// fill a 64x32 bf16 tile (rows stride ld) into LDS [64][TW]; 256 threads x 16B
__device__ __forceinline__ void fillA(bf16* dst, const bf16* srcRowBase, int ld) {
    int t = threadIdx.x; int r = t >> 2; int kq = (t & 3) << 3;
    *(float4*)(dst + r * TW + kq) = *(const float4*)(srcRowBase + (size_t)r * ld + kq);
}
// MFMA fragment: sub-tile 'sub' (16 rows), lane l: row=sub*16+(l&15), k=(l>>4)*8
__device__ __forceinline__ v8bf ldfrag(const bf16* tile, int sub, int l) {
    return *(const v8bf*)(tile + (size_t)(sub * 16 + (l & 15)) * TW + ((l >> 4) << 3));
}

// ---------------- fused layer stage A: dist (upper-tri tiles) + st ----------------
// 1D grid, XCD-pinned: z = (i>>1)&3, bi = ((i>>3)<<1)|(i&1)  (batch z -> XCDs {2z,2z+1})
__global__ __launch_bounds__(256) void k_layer_a(const bf16* __restrict__ Xhi, const bf16* __restrict__ Xlo,
                                                 int ld, int Kpad, size_t xstride,
                                                 const bf16* __restrict__ Whi, const bf16* __restrict__ Wlo,
                                                 int O, const float* __restrict__ sqg,
                                                 float* __restrict__ Dg, float* __restrict__ Pg,
                                                 const int* __restrict__ flag) {
    int i = blockIdx.x;
    int z = (i >> 1) & 3;
    int bi = ((i >> 3) << 1) | (i & 1);
    const bf16* Xh = Xhi + (size_t)z * xstride;
    const bf16* Xl = Xlo + (size_t)z * xstride;
    __shared__ alignas(16) bf16 Ah[64 * TW], Al[64 * TW], Bh[64 * TW], Bl[64 * TW];
    int w = threadIdx.x >> 6, l = threadIdx.x & 63;
    int quad = l >> 4, col = l & 15;
    v4f zero = {0.f, 0.f, 0.f, 0.f};
    v4f acc[4] = {zero, zero, zero, zero};

    if (bi < 136) {
        // ---- dist tile: triangular decode, bx >= by ----
        int bx = 0;
        while ((((bx + 1) * (bx + 2)) >> 1) <= bi) bx++;
        int by = bi - ((bx * (bx + 1)) >> 1);
        const float* sq = sqg + z * NPTS;
        float* D = Dg + (size_t)z * NPTS * NPTS;
        int n0 = by * 64, m0 = bx * 64;
        for (int k0 = 0; k0 < Kpad; k0 += 32) {
            __syncthreads();
            fillA(Ah, Xh + (size_t)n0 * ld + k0, ld);
            fillA(Bh, Xh + (size_t)m0 * ld + k0, ld);
            fillA(Al, Xl + (size_t)n0 * ld + k0, ld);
            fillA(Bl, Xl + (size_t)m0 * ld + k0, ld);
            __syncthreads();
            v8bf ah = ldfrag(Ah, w, l);
            v8bf al = ldfrag(Al, w, l);
#pragma unroll
            for (int nt = 0; nt < 4; nt++) {
                v8bf bh = ldfrag(Bh, nt, l);
                v8bf bl = ldfrag(Bl, nt, l);
                acc[nt] = __builtin_amdgcn_mfma_f32_16x16x32_bf16(ah, bh, acc[nt], 0, 0, 0);
                acc[nt] = __builtin_amdgcn_mfma_f32_16x16x32_bf16(ah, bl, acc[nt], 0, 0, 0);
                acc[nt] = __builtin_amdgcn_mfma_f32_16x16x32_bf16(al, bh, acc[nt], 0, 0, 0);
            }
        }
        int nb = n0 + 16 * w + quad * 4;
        float sm[4];
#pragma unroll
        for (int nt = 0; nt < 4; nt++) sm[nt] = sq[m0 + nt * 16 + col];
#pragma unroll
        for (int r = 0; r < 4; r++) {
            float sn = sq[nb + r];
#pragma unroll
            for (int nt = 0; nt < 4; nt++) {
                float d = 2.f * acc[nt][r] - sn - sm[nt];
                int m = m0 + nt * 16 + col;
                D[(size_t)(nb + r) * NPTS + m] = d;
                if (bx != by) D[(size_t)m * NPTS + nb + r] = d;
            }
        }
    } else {
        // ---- st tile ----
        int isf = *flag;
        int nTilesO = (2 * O) >> 6;
        int s = bi - 136;
        int n0 = (s % nTilesO) * 64;   // weight-row tile (over 2O)
        int m0 = (s / nTilesO) * 64;   // point tile (over 1024)
        int N2 = 2 * O;
        float* P = Pg + (size_t)z * NPTS * N2;
        for (int k0 = 0; k0 < Kpad; k0 += 32) {
            __syncthreads();
            fillA(Ah, Xh + (size_t)m0 * ld + k0, ld);
            fillA(Al, Xl + (size_t)m0 * ld + k0, ld);
            fillA(Bh, Whi + (size_t)n0 * Kpad + k0, Kpad);
            if (isf) fillA(Bl, Wlo + (size_t)n0 * Kpad + k0, Kpad);
            __syncthreads();
            v8bf ah = ldfrag(Ah, w, l);
            v8bf al = ldfrag(Al, w, l);
#pragma unroll
            for (int nt = 0; nt < 4; nt++) {
                v8bf bh = ldfrag(Bh, nt, l);
                acc[nt] = __builtin_amdgcn_mfma_f32_16x16x32_bf16(ah, bh, acc[nt], 0, 0, 0);
                acc[nt] = __builtin_amdgcn_mfma_f32_16x16x32_bf16(al, bh, acc[nt], 0, 0, 0);
                if (isf) {
                    v8bf bl = ldfrag(Bl, nt, l);
                    acc[nt] = __builtin_amdgcn_mfma_f32_16x16x32_bf16(ah, bl, acc[nt], 0, 0, 0);
                }
            }
        }
        int rb = m0 + 16 * w + quad * 4;
#pragma unroll
        for (int r = 0; r < 4; r++)
#pragma unroll
            for (int nt = 0; nt < 4; nt++)
                P[(size_t)(rb + r) * N2 + n0 + nt * 16 + col] = acc[nt][r];
    }
}

// ---------------- fused stage B: top-20 (wave per row, 4 rows/block) + gather-max ----------------
// 1D grid 1024, XCD-pinned: z = (i>>1)&3, local = ((i>>3)<<1)|(i&1); rows local*4+q (wave q)
__global__ __launch_bounds__(256) void k_layer_b(const float* __restrict__ Dg, const float* __restrict__ Pg,
                                                 const void* __restrict__ g, const void* __restrict__ bias,
                                                 int O, bf16* __restrict__ xhOut, bf16* __restrict__ xlOut,
                                                 float* __restrict__ sqOut, int writeSq,
                                                 const int* __restrict__ flag) {
    __shared__ int ids[4][20];
    __shared__ float sqP[4][8];
    int isf = *flag;
    int i = blockIdx.x;
    int z = (i >> 1) & 3;
    int local = ((i >> 3) << 1) | (i & 1);
    int tid = threadIdx.x;
    int wq = tid >> 6, l = tid & 63;
    int row = local * 4 + wq;

    // ---- per-wave register-resident top-20 (identical to round-12 k_topk) ----
    {
        const float* Dr = Dg + (size_t)z * NPTS * NPTS + (size_t)row * NPTS;
        float v[16];
#pragma unroll
        for (int j = 0; j < 16; j++) v[j] = Dr[j * 64 + l];
        for (int s = 0; s < 20; s++) {
            float bv = v[0]; int bj = 0;
#pragma unroll
            for (int j = 1; j < 16; j++)
                if (v[j] > bv) { bv = v[j]; bj = j; }   // ascending keeps min j on tie
            int bi = bj * 64 + l;
#pragma unroll
            for (int off = 1; off < 64; off <<= 1) {   // xor butterfly: all lanes converge
                float ov = __shfl_xor(bv, off);
                int   oi = __shfl_xor(bi, off);
                if (ov > bv || (ov == bv && oi < bi)) { bv = ov; bi = oi; }
            }
            if (l == 0) ids[wq][s] = bi;
            if ((bi & 63) == l) {
                int ej = bi >> 6;
#pragma unroll
                for (int j = 0; j < 16; j++)
                    if (j == ej) v[j] = -__builtin_inff();
            }
        }
    }
    __syncthreads();

    // ---- gather + affine + lrelu + max over k for the block's 4 rows ----
    int N2 = 2 * O;
    const float* P = Pg + (size_t)z * NPTS * N2;
    for (int it = tid; it < 4 * O; it += 256) {
        int r = it / O, o = it % O;         // wave-contiguous: one row+chunk per wave
        int n = local * 4 + r;
        float tv = P[(size_t)n * N2 + O + o] - P[(size_t)n * N2 + o];
        float scl = ldw(g, o, isf) * BN_SCALE;
        float bb = ldw(bias, o, isf);
        float acc = -__builtin_inff();
        for (int j = 0; j < 20; j++) {
            int m = ids[r][j];
            float v = P[(size_t)m * N2 + o] + tv;
            float z2 = v * scl + bb;
            z2 = z2 > 0.f ? z2 : 0.2f * z2;
            acc = fmaxf(acc, z2);
        }
        bf16 hi = f2b(acc);
        bf16 lo = f2b(acc - b2f(hi));
        xhOut[(size_t)z * NPTS * 960 + (size_t)n * 960 + o] = hi;
        xlOut[(size_t)z * NPTS * 960 + (size_t)n * 960 + o] = lo;
        if (writeSq) {
            float xv = b2f(hi) + b2f(lo);
            float s = xv * xv;
#pragma unroll
            for (int off = 32; off > 0; off >>= 1) s += __shfl_down(s, off);
            if (l == 0) sqP[r][o >> 6] = s;   // fixed chunk slot: deterministic order
        }
    }
    if (writeSq) {
        __syncthreads();
        if (tid < 4) {
            int nc = O >> 6;
            float tot = 0.f;
            for (int c = 0; c < nc; c++) tot += sqP[tid][c];
            sqOut[z * NPTS + local * 4 + tid] = tot;
        }
    }
}

// ---------------- conv5 via MFMA (pre-split W5) + fused affine/lrelu/max-pool ----------------
// 1D grid 512, XCD-pinned: z = (i>>1)&3, wi = ((i>>3)<<1)|(i&1); o0=(wi&7)*64, m0=(wi>>3)*64
__global__ __launch_bounds__(256) void k_conv5(const bf16* __restrict__ Xhi, const bf16* __restrict__ Xlo,
                                               const bf16* __restrict__ Whi, const bf16* __restrict__ Wlo,
                                               const void* __restrict__ g, const void* __restrict__ bias,
                                               unsigned* __restrict__ pooledU,
                                               const int* __restrict__ flag) {
    int isf = *flag;
    int i = blockIdx.x;
    int z = (i >> 1) & 3;
    int wi = ((i >> 3) << 1) | (i & 1);
    int o0 = (wi & 7) * 64, m0 = (wi >> 3) * 64;
    const bf16* Xh = Xhi + (size_t)z * NPTS * 960;
    const bf16* Xl = Xlo + (size_t)z * NPTS * 960;
    __shared__ alignas(16) bf16 Ah[64 * TW], Al[64 * TW], Bh[64 * TW], Bl[64 * TW];
    __shared__ float red[4][4][16];
    int w = threadIdx.x >> 6, l = threadIdx.x & 63;
    v4f zero = {0.f, 0.f, 0.f, 0.f};
    v4f acc[4] = {zero, zero, zero, zero};
    for (int k0 = 0; k0 < 960; k0 += 32) {
        __syncthreads();
        fillA(Ah, Xh + (size_t)m0 * 960 + k0, 960);
        fillA(Al, Xl + (size_t)m0 * 960 + k0, 960);
        fillA(Bh, Whi + (size_t)o0 * 960 + k0, 960);
        if (isf) fillA(Bl, Wlo + (size_t)o0 * 960 + k0, 960);
        __syncthreads();
        v8bf ah = ldfrag(Ah, w, l);
        v8bf al = ldfrag(Al, w, l);
#pragma unroll
        for (int nt = 0; nt < 4; nt++) {
            v8bf bh = ldfrag(Bh, nt, l);
            acc[nt] = __builtin_amdgcn_mfma_f32_16x16x32_bf16(ah, bh, acc[nt], 0, 0, 0);
            acc[nt] = __builtin_amdgcn_mfma_f32_16x16x32_bf16(al, bh, acc[nt], 0, 0, 0);
            if (isf) {
                v8bf bl = ldfrag(Bl, nt, l);
                acc[nt] = __builtin_amdgcn_mfma_f32_16x16x32_bf16(ah, bl, acc[nt], 0, 0, 0);
            }
        }
    }
    int quad = l >> 4, col = l & 15;
#pragma unroll
    for (int nt = 0; nt < 4; nt++) {
        int o = o0 + nt * 16 + col;
        float scl = ldw(g, o, isf) * BN_SCALE;
        float bi = ldw(bias, o, isf);
        float ym = -__builtin_inff();
#pragma unroll
        for (int r = 0; r < 4; r++) {
            float v = acc[nt][r] * scl + bi;
            v = v > 0.f ? v : 0.2f * v;
            ym = fmaxf(ym, v);
        }
        ym = fmaxf(ym, __shfl_down(ym, 32));
        ym = fmaxf(ym, __shfl_down(ym, 16));
        if (quad == 0) red[w][nt][col] = ym;
    }
    __syncthreads();
    if (threadIdx.x < 64) {
        int nt = threadIdx.x >> 4, c = threadIdx.x & 15;
        float m = fmaxf(fmaxf(red[0][nt][c], red[1][nt][c]), fmaxf(red[2][nt][c], red[3][nt][c]));
        atomicMax(&pooledU[z * 512 + o0 + nt * 16 + c], ordf(m));
    }
}

// ---------------- final linear: coalesced wave-per-output ----------------
__global__ void k_final(const unsigned* __restrict__ pooledU, const void* __restrict__ We,
                        void* __restrict__ out, const int* __restrict__ flag) {
    __shared__ float p[512];
    int isf = *flag;
    int b = blockIdx.x >> 2, fb = blockIdx.x & 3;
    int t = threadIdx.x, w = t >> 6, l = t & 63;
    for (int i = t; i < 512; i += 256) p[i] = iordf(pooledU[b * 512 + i]);
    __syncthreads();
    for (int it = 0; it < 16; it++) {
        int f = fb * 64 + w * 16 + it;
        float s = 0.f;
        size_t base = (size_t)f * 512 + l * 8;
#pragma unroll
        for (int j = 0; j < 8; j++) s += p[l * 8 + j] * ldw(We, base + j, isf);
#pragma unroll
        for (int off = 32; off > 0; off >>= 1) s += __shfl_down(s, off);
        if (l == 0) {
            if (isf) ((float*)out)[b * 256 + f] = s;
            else     ((bf16*)out)[b * 256 + f] = f2b(s);
        }
    }
}

extern "C" void kernel_launch(void* const* d_in, const int* in_sizes, int n_in,
                              void* d_out, int out_size, void* d_ws, size_t ws_size,
                              hipStream_t stream) {
    const void* x  = d_in[0];
    const void* Wl[4] = { d_in[1], d_in[4], d_in[7], d_in[10] };
    const void* gl[4] = { d_in[2], d_in[5], d_in[8], d_in[11] };
    const void* bl[4] = { d_in[3], d_in[6], d_in[9], d_in[12] };
    const void* W5 = d_in[13];
    const void* g5 = d_in[14];
    const void* b5 = d_in[15];
    const void* We = d_in[16];

    // workspace layout (bytes), total ~53.5 MB (ws ~256 MiB per round-9 fill evidence)
    char* base = (char*)d_ws;
    bf16*     xc_hi   = (bf16*)(base);                  // 7,864,320
    bf16*     xc_lo   = (bf16*)(base + 7864320);        // 7,864,320
    bf16*     xpadh   = (bf16*)(base + 15728640);       // 262,144
    bf16*     xpadl   = (bf16*)(base + 15990784);       // 262,144
    float*    Dbuf    = (float*)(base + 16252928);      // 16,777,216
    float*    Pbuf    = (float*)(base + 33030144);      // 16,777,216
    bf16*     Whi     = (bf16*)(base + 49807360);       // 1,679,360
    bf16*     Wlo     = (bf16*)(base + 51486720);       // 1,679,360
    unsigned* pooledU = (unsigned*)(base + 53493760);   // 8,192
    float*    sq      = (float*)(base + 53501952);      // 16,384
    int*      flag    = (int*)(base + 53518336);        // 4

    const int Kpad[4]   = { 32, 64, 128, 256 };
    const int Os[4]     = { 64, 128, 256, 512 };
    const int Woff[5]   = { 0, 4096, 20480, 86016, 348160 };
    const int colIn[4]  = { 0, 0, 64, 192 };
    const int colOut[4] = { 0, 64, 192, 448 };

    k_probe<<<1, 256, 0, stream>>>(x, flag, pooledU);
    k_prep<<<3296, 256, 0, stream>>>(Wl[0], Wl[1], Wl[2], Wl[3], W5, x,
                                     Whi, Wlo, xpadh, xpadl, sq, flag);

    for (int l = 0; l < 4; l++) {
        int O = Os[l];
        int nTilesO = (2 * O) >> 6;
        int nBlk = 136 + 16 * nTilesO;  // even for all layers
        const bf16* Xh = (l == 0) ? xpadh : (xc_hi + colIn[l]);
        const bf16* Xl = (l == 0) ? xpadl : (xc_lo + colIn[l]);
        int ld = (l == 0) ? 32 : 960;
        size_t xstr = (l == 0) ? (size_t)NPTS * 32 : (size_t)NPTS * 960;
        k_layer_a<<<nBlk * NB, 256, 0, stream>>>(
            Xh, Xl, ld, Kpad[l], xstr, Whi + Woff[l], Wlo + Woff[l], O, sq, Dbuf, Pbuf, flag);
        k_layer_b<<<NPTS * NB / 4, 256, 0, stream>>>(
            Dbuf, Pbuf, gl[l], bl[l], O, xc_hi + colOut[l], xc_lo + colOut[l], sq, l < 3, flag);
    }
    k_conv5<<<512, 256, 0, stream>>>(xc_hi, xc_lo, Whi + Woff[4], Wlo + Woff[4],
                                     g5, b5, pooledU, flag);
    k_final<<<16, 256, 0, stream>>>(pooledU, We, d_out, flag);
}

// Round 15
// 345.327 us; speedup vs baseline: 4.0627x; 1.0069x over previous
//
#include <hip/hip_runtime.h>
#include <hip/hip_bf16.h>
#include <math.h>

typedef __hip_bfloat16 bf16;
typedef __bf16 v8bf __attribute__((ext_vector_type(8)));
typedef float v4f __attribute__((ext_vector_type(4)));

#define BN_SCALE 0.9999950000374997f
#define NPTS 1024
#define NB 4
#define TW 40  // LDS tile row stride in bf16 (80B: 2-way bank alias only = free)

__device__ __forceinline__ float b2f(bf16 v) { return __bfloat162float(v); }
__device__ __forceinline__ bf16 f2b(float v) { return __float2bfloat16(v); }
__device__ __forceinline__ float ldw(const void* p, size_t i, int isf) {
    return isf ? ((const float*)p)[i] : b2f(((const bf16*)p)[i]);
}
__device__ __forceinline__ unsigned ordf(float f) {
    unsigned u = __float_as_uint(f);
    return (u & 0x80000000u) ? ~u : (u | 0x80000000u);
}
__device__ __forceinline__ float iordf(unsigned u) {
    return (u & 0x80000000u) ? __uint_as_float(u ^ 0x80000000u) : __uint_as_float(~u);
}

// per-block dtype detect from first 512 shorts of x (fp32 ~113/256 implausible, bf16 ~0)
__device__ __forceinline__ int detect_isf(const void* xraw, int* cnt) {
    const unsigned short* u = (const unsigned short*)xraw;
    int t = threadIdx.x, c = 0;
    for (int i = t; i < 512; i += 256) {
        unsigned short v = u[i];
        int e = (v >> 7) & 0xFF;
        int m = v & 0x7F;
        if (e == 0xFF || e >= 141 || (e == 0 && m != 0)) c++;
    }
    cnt[t] = c;
    __syncthreads();
    for (int off = 128; off > 0; off >>= 1) {
        if (t < off) cnt[t] += cnt[t + off];
        __syncthreads();
    }
    int isf = (cnt[0] > 30) ? 1 : 0;
    __syncthreads();
    return isf;
}

// ---------------- fused prep: dtype flag + pooled init + weight splits + x pad + sq ----------------
__global__ void k_prep(const void* __restrict__ W1, const void* __restrict__ W2,
                       const void* __restrict__ W3, const void* __restrict__ W4,
                       const void* __restrict__ W5, const void* __restrict__ x,
                       bf16* __restrict__ Whi, bf16* __restrict__ Wlo,
                       bf16* __restrict__ xph, bf16* __restrict__ xpl, float* __restrict__ sq,
                       int* __restrict__ flag, unsigned* __restrict__ pooledU) {
    __shared__ int cnt[256];
    int isf = detect_isf(x, cnt);
    if (blockIdx.x == 0) {
        if (threadIdx.x == 0) *flag = isf;
        for (int i = threadIdx.x; i < 2048; i += 256) pooledU[i] = 0u;  // 0 < ordf(any finite)
    }
    int idx = blockIdx.x * 256 + threadIdx.x;
    if (idx < 839680) {
        const void* src; int C, O, Kpad, two, local;
        if (idx < 4096)        { src = W1; C = 3;   O = 64;  Kpad = 32;  two = 1; local = idx; }
        else if (idx < 20480)  { src = W2; C = 64;  O = 128; Kpad = 64;  two = 1; local = idx - 4096; }
        else if (idx < 86016)  { src = W3; C = 128; O = 256; Kpad = 128; two = 1; local = idx - 20480; }
        else if (idx < 348160) { src = W4; C = 256; O = 512; Kpad = 256; two = 1; local = idx - 86016; }
        else                   { src = W5; C = 960; O = 512; Kpad = 960; two = 0; local = idx - 348160; }
        int r = local / Kpad, c = local % Kpad;
        float wv = 0.f;
        if (c < C) {
            size_t off;
            if (two) off = (r < O) ? (size_t)r * 2 * C + c : (size_t)(r - O) * 2 * C + C + c;
            else     off = (size_t)r * C + c;
            wv = ldw(src, off, isf);
        }
        bf16 h = f2b(wv);
        Whi[idx] = h;
        Wlo[idx] = f2b(wv - b2f(h));
    } else if (idx < 843776) {
        int p = idx - 839680;       // point index: z*1024 + n
        int z = p >> 10, n = p & 1023;
        bf16* ph = xph + (size_t)z * NPTS * 32;
        bf16* pl = xpl + (size_t)z * NPTS * 32;
        float s = 0.f;
        for (int c = 0; c < 32; c++) {
            float v = (c < 3) ? ldw(x, (size_t)z * NPTS * 3 + n * 3 + c, isf) : 0.f;
            bf16 h = f2b(v);
            ph[n * 32 + c] = h;
            pl[n * 32 + c] = f2b(v - b2f(h));
            s += v * v;
        }
        sq[z * NPTS + n] = s;
    }
}

// fill a 64x32 bf16 tile (rows stride ld) into LDS [64][TW]; 256 threads x 16B
__device__ __forceinline__ void fillA(bf16* dst, const bf16* srcRowBase, int ld) {
    int t = threadIdx.x; int r = t >> 2; int kq = (t & 3) << 3;
    *(float4*)(dst + r * TW + kq) = *(const float4*)(srcRowBase + (size_t)r * ld + kq);
}
// MFMA fragment: sub-tile 'sub' (16 rows), lane l: row=sub*16+(l&15), k=(l>>4)*8
__device__ __forceinline__ v8bf ldfrag(const bf16* tile, int sub, int l) {
    return *(const v8bf*)(tile + (size_t)(sub * 16 + (l & 15)) * TW + ((l >> 4) << 3));
}

// ---------------- fused layer stage A: dist (upper-tri tiles) + st ----------------
// 1D grid, XCD-pinned: z = (i>>1)&3, bi = ((i>>3)<<1)|(i&1)  (batch z -> XCDs {2z,2z+1})
__global__ __launch_bounds__(256) void k_layer_a(const bf16* __restrict__ Xhi, const bf16* __restrict__ Xlo,
                                                 int ld, int Kpad, size_t xstride,
                                                 const bf16* __restrict__ Whi, const bf16* __restrict__ Wlo,
                                                 int O, const float* __restrict__ sqg,
                                                 float* __restrict__ Dg, float* __restrict__ Pg,
                                                 const int* __restrict__ flag) {
    int i = blockIdx.x;
    int z = (i >> 1) & 3;
    int bi = ((i >> 3) << 1) | (i & 1);
    const bf16* Xh = Xhi + (size_t)z * xstride;
    const bf16* Xl = Xlo + (size_t)z * xstride;
    __shared__ alignas(16) bf16 Ah[64 * TW], Al[64 * TW], Bh[64 * TW], Bl[64 * TW];
    int w = threadIdx.x >> 6, l = threadIdx.x & 63;
    int quad = l >> 4, col = l & 15;
    v4f zero = {0.f, 0.f, 0.f, 0.f};
    v4f acc[4] = {zero, zero, zero, zero};

    if (bi < 136) {
        // ---- dist tile: triangular decode, bx >= by ----
        int bx = 0;
        while ((((bx + 1) * (bx + 2)) >> 1) <= bi) bx++;
        int by = bi - ((bx * (bx + 1)) >> 1);
        const float* sq = sqg + z * NPTS;
        float* D = Dg + (size_t)z * NPTS * NPTS;
        int n0 = by * 64, m0 = bx * 64;
        for (int k0 = 0; k0 < Kpad; k0 += 32) {
            __syncthreads();
            fillA(Ah, Xh + (size_t)n0 * ld + k0, ld);
            fillA(Bh, Xh + (size_t)m0 * ld + k0, ld);
            fillA(Al, Xl + (size_t)n0 * ld + k0, ld);
            fillA(Bl, Xl + (size_t)m0 * ld + k0, ld);
            __syncthreads();
            v8bf ah = ldfrag(Ah, w, l);
            v8bf al = ldfrag(Al, w, l);
#pragma unroll
            for (int nt = 0; nt < 4; nt++) {
                v8bf bh = ldfrag(Bh, nt, l);
                v8bf bl = ldfrag(Bl, nt, l);
                acc[nt] = __builtin_amdgcn_mfma_f32_16x16x32_bf16(ah, bh, acc[nt], 0, 0, 0);
                acc[nt] = __builtin_amdgcn_mfma_f32_16x16x32_bf16(ah, bl, acc[nt], 0, 0, 0);
                acc[nt] = __builtin_amdgcn_mfma_f32_16x16x32_bf16(al, bh, acc[nt], 0, 0, 0);
            }
        }
        int nb = n0 + 16 * w + quad * 4;
        float sm[4];
#pragma unroll
        for (int nt = 0; nt < 4; nt++) sm[nt] = sq[m0 + nt * 16 + col];
#pragma unroll
        for (int r = 0; r < 4; r++) {
            float sn = sq[nb + r];
#pragma unroll
            for (int nt = 0; nt < 4; nt++) {
                float d = 2.f * acc[nt][r] - sn - sm[nt];
                int m = m0 + nt * 16 + col;
                D[(size_t)(nb + r) * NPTS + m] = d;
                if (bx != by) D[(size_t)m * NPTS + nb + r] = d;
            }
        }
    } else {
        // ---- st tile ----
        int isf = *flag;
        int nTilesO = (2 * O) >> 6;
        int s = bi - 136;
        int n0 = (s % nTilesO) * 64;   // weight-row tile (over 2O)
        int m0 = (s / nTilesO) * 64;   // point tile (over 1024)
        int N2 = 2 * O;
        float* P = Pg + (size_t)z * NPTS * N2;
        for (int k0 = 0; k0 < Kpad; k0 += 32) {
            __syncthreads();
            fillA(Ah, Xh + (size_t)m0 * ld + k0, ld);
            fillA(Al, Xl + (size_t)m0 * ld + k0, ld);
            fillA(Bh, Whi + (size_t)n0 * Kpad + k0, Kpad);
            if (isf) fillA(Bl, Wlo + (size_t)n0 * Kpad + k0, Kpad);
            __syncthreads();
            v8bf ah = ldfrag(Ah, w, l);
            v8bf al = ldfrag(Al, w, l);
#pragma unroll
            for (int nt = 0; nt < 4; nt++) {
                v8bf bh = ldfrag(Bh, nt, l);
                acc[nt] = __builtin_amdgcn_mfma_f32_16x16x32_bf16(ah, bh, acc[nt], 0, 0, 0);
                acc[nt] = __builtin_amdgcn_mfma_f32_16x16x32_bf16(al, bh, acc[nt], 0, 0, 0);
                if (isf) {
                    v8bf bl = ldfrag(Bl, nt, l);
                    acc[nt] = __builtin_amdgcn_mfma_f32_16x16x32_bf16(ah, bl, acc[nt], 0, 0, 0);
                }
            }
        }
        int rb = m0 + 16 * w + quad * 4;
#pragma unroll
        for (int r = 0; r < 4; r++)
#pragma unroll
            for (int nt = 0; nt < 4; nt++)
                P[(size_t)(rb + r) * N2 + n0 + nt * 16 + col] = acc[nt][r];
    }
}

// ---------------- fused stage B: top-20 (wave per row, 4 rows/block) + gather-max ----------------
// 1D grid 1024, XCD-pinned: z = (i>>1)&3, local = ((i>>3)<<1)|(i&1); rows local*4+q (wave q)
__global__ __launch_bounds__(256) void k_layer_b(const float* __restrict__ Dg, const float* __restrict__ Pg,
                                                 const void* __restrict__ g, const void* __restrict__ bias,
                                                 int O, bf16* __restrict__ xhOut, bf16* __restrict__ xlOut,
                                                 float* __restrict__ sqOut, int writeSq,
                                                 const int* __restrict__ flag) {
    __shared__ int ids[4][20];
    __shared__ float sqP[4][8];
    int isf = *flag;
    int i = blockIdx.x;
    int z = (i >> 1) & 3;
    int local = ((i >> 3) << 1) | (i & 1);
    int tid = threadIdx.x;
    int wq = tid >> 6, l = tid & 63;
    int row = local * 4 + wq;

    // ---- per-wave register-resident top-20 (float4 loads; selection semantics identical:
    //      lane->index map bi = jj*256 + l*4 + q is bijective over [0,1024), monotone per
    //      lane in scan order -> min-index tie-break preserved; butterfly uses global bi) ----
    {
        const float* Dr = Dg + (size_t)z * NPTS * NPTS + (size_t)row * NPTS;
        float v[16];
#pragma unroll
        for (int jj = 0; jj < 4; jj++) {
            float4 f4 = *(const float4*)(Dr + jj * 256 + l * 4);
            v[jj * 4 + 0] = f4.x; v[jj * 4 + 1] = f4.y;
            v[jj * 4 + 2] = f4.z; v[jj * 4 + 3] = f4.w;
        }
        for (int s = 0; s < 20; s++) {
            float bv = v[0]; int bj = 0;
#pragma unroll
            for (int j = 1; j < 16; j++)
                if (v[j] > bv) { bv = v[j]; bj = j; }   // ascending keeps min global idx on tie
            int bi = (bj >> 2) * 256 + l * 4 + (bj & 3);
#pragma unroll
            for (int off = 1; off < 64; off <<= 1) {   // xor butterfly: all lanes converge
                float ov = __shfl_xor(bv, off);
                int   oi = __shfl_xor(bi, off);
                if (ov > bv || (ov == bv && oi < bi)) { bv = ov; bi = oi; }
            }
            if (l == 0) ids[wq][s] = bi;
            if (((bi >> 2) & 63) == l) {               // owning lane evicts
                int ej = (bi >> 8) * 4 + (bi & 3);
#pragma unroll
                for (int j = 0; j < 16; j++)
                    if (j == ej) v[j] = -__builtin_inff();
            }
        }
    }
    __syncthreads();

    // ---- gather + affine + lrelu + max over k for the block's 4 rows ----
    int N2 = 2 * O;
    const float* P = Pg + (size_t)z * NPTS * N2;
    for (int it = tid; it < 4 * O; it += 256) {
        int r = it / O, o = it % O;         // wave-contiguous: one row+chunk per wave
        int n = local * 4 + r;
        float tv = P[(size_t)n * N2 + O + o] - P[(size_t)n * N2 + o];
        float scl = ldw(g, o, isf) * BN_SCALE;
        float bb = ldw(bias, o, isf);
        float acc = -__builtin_inff();
        for (int j = 0; j < 20; j++) {
            int m = ids[r][j];
            float v = P[(size_t)m * N2 + o] + tv;
            float z2 = v * scl + bb;
            z2 = z2 > 0.f ? z2 : 0.2f * z2;
            acc = fmaxf(acc, z2);
        }
        bf16 hi = f2b(acc);
        bf16 lo = f2b(acc - b2f(hi));
        xhOut[(size_t)z * NPTS * 960 + (size_t)n * 960 + o] = hi;
        xlOut[(size_t)z * NPTS * 960 + (size_t)n * 960 + o] = lo;
        if (writeSq) {
            float xv = b2f(hi) + b2f(lo);
            float s = xv * xv;
#pragma unroll
            for (int off = 32; off > 0; off >>= 1) s += __shfl_down(s, off);
            if (l == 0) sqP[r][o >> 6] = s;   // fixed chunk slot: deterministic order
        }
    }
    if (writeSq) {
        __syncthreads();
        if (tid < 4) {
            int nc = O >> 6;
            float tot = 0.f;
            for (int c = 0; c < nc; c++) tot += sqP[tid][c];
            sqOut[z * NPTS + local * 4 + tid] = tot;
        }
    }
}

// ---------------- conv5 via MFMA (pre-split W5) + fused affine/lrelu/max-pool ----------------
// 1D grid 512, XCD-pinned: z = (i>>1)&3, wi = ((i>>3)<<1)|(i&1); o0=(wi&7)*64, m0=(wi>>3)*64
__global__ __launch_bounds__(256) void k_conv5(const bf16* __restrict__ Xhi, const bf16* __restrict__ Xlo,
                                               const bf16* __restrict__ Whi, const bf16* __restrict__ Wlo,
                                               const void* __restrict__ g, const void* __restrict__ bias,
                                               unsigned* __restrict__ pooledU,
                                               const int* __restrict__ flag) {
    int isf = *flag;
    int i = blockIdx.x;
    int z = (i >> 1) & 3;
    int wi = ((i >> 3) << 1) | (i & 1);
    int o0 = (wi & 7) * 64, m0 = (wi >> 3) * 64;
    const bf16* Xh = Xhi + (size_t)z * NPTS * 960;
    const bf16* Xl = Xlo + (size_t)z * NPTS * 960;
    __shared__ alignas(16) bf16 Ah[64 * TW], Al[64 * TW], Bh[64 * TW], Bl[64 * TW];
    __shared__ float red[4][4][16];
    int w = threadIdx.x >> 6, l = threadIdx.x & 63;
    v4f zero = {0.f, 0.f, 0.f, 0.f};
    v4f acc[4] = {zero, zero, zero, zero};
    for (int k0 = 0; k0 < 960; k0 += 32) {
        __syncthreads();
        fillA(Ah, Xh + (size_t)m0 * 960 + k0, 960);
        fillA(Al, Xl + (size_t)m0 * 960 + k0, 960);
        fillA(Bh, Whi + (size_t)o0 * 960 + k0, 960);
        if (isf) fillA(Bl, Wlo + (size_t)o0 * 960 + k0, 960);
        __syncthreads();
        v8bf ah = ldfrag(Ah, w, l);
        v8bf al = ldfrag(Al, w, l);
#pragma unroll
        for (int nt = 0; nt < 4; nt++) {
            v8bf bh = ldfrag(Bh, nt, l);
            acc[nt] = __builtin_amdgcn_mfma_f32_16x16x32_bf16(ah, bh, acc[nt], 0, 0, 0);
            acc[nt] = __builtin_amdgcn_mfma_f32_16x16x32_bf16(al, bh, acc[nt], 0, 0, 0);
            if (isf) {
                v8bf bl = ldfrag(Bl, nt, l);
                acc[nt] = __builtin_amdgcn_mfma_f32_16x16x32_bf16(ah, bl, acc[nt], 0, 0, 0);
            }
        }
    }
    int quad = l >> 4, col = l & 15;
#pragma unroll
    for (int nt = 0; nt < 4; nt++) {
        int o = o0 + nt * 16 + col;
        float scl = ldw(g, o, isf) * BN_SCALE;
        float bi = ldw(bias, o, isf);
        float ym = -__builtin_inff();
#pragma unroll
        for (int r = 0; r < 4; r++) {
            float v = acc[nt][r] * scl + bi;
            v = v > 0.f ? v : 0.2f * v;
            ym = fmaxf(ym, v);
        }
        ym = fmaxf(ym, __shfl_down(ym, 32));
        ym = fmaxf(ym, __shfl_down(ym, 16));
        if (quad == 0) red[w][nt][col] = ym;
    }
    __syncthreads();
    if (threadIdx.x < 64) {
        int nt = threadIdx.x >> 4, c = threadIdx.x & 15;
        float m = fmaxf(fmaxf(red[0][nt][c], red[1][nt][c]), fmaxf(red[2][nt][c], red[3][nt][c]));
        atomicMax(&pooledU[z * 512 + o0 + nt * 16 + c], ordf(m));
    }
}

// ---------------- final linear: coalesced wave-per-output ----------------
__global__ void k_final(const unsigned* __restrict__ pooledU, const void* __restrict__ We,
                        void* __restrict__ out, const int* __restrict__ flag) {
    __shared__ float p[512];
    int isf = *flag;
    int b = blockIdx.x >> 2, fb = blockIdx.x & 3;
    int t = threadIdx.x, w = t >> 6, l = t & 63;
    for (int i = t; i < 512; i += 256) p[i] = iordf(pooledU[b * 512 + i]);
    __syncthreads();
    for (int it = 0; it < 16; it++) {
        int f = fb * 64 + w * 16 + it;
        float s = 0.f;
        size_t base = (size_t)f * 512 + l * 8;
#pragma unroll
        for (int j = 0; j < 8; j++) s += p[l * 8 + j] * ldw(We, base + j, isf);
#pragma unroll
        for (int off = 32; off > 0; off >>= 1) s += __shfl_down(s, off);
        if (l == 0) {
            if (isf) ((float*)out)[b * 256 + f] = s;
            else     ((bf16*)out)[b * 256 + f] = f2b(s);
        }
    }
}

extern "C" void kernel_launch(void* const* d_in, const int* in_sizes, int n_in,
                              void* d_out, int out_size, void* d_ws, size_t ws_size,
                              hipStream_t stream) {
    const void* x  = d_in[0];
    const void* Wl[4] = { d_in[1], d_in[4], d_in[7], d_in[10] };
    const void* gl[4] = { d_in[2], d_in[5], d_in[8], d_in[11] };
    const void* bl[4] = { d_in[3], d_in[6], d_in[9], d_in[12] };
    const void* W5 = d_in[13];
    const void* g5 = d_in[14];
    const void* b5 = d_in[15];
    const void* We = d_in[16];

    // workspace layout (bytes), total ~53.5 MB (ws ~256 MiB per round-9 fill evidence)
    char* base = (char*)d_ws;
    bf16*     xc_hi   = (bf16*)(base);                  // 7,864,320
    bf16*     xc_lo   = (bf16*)(base + 7864320);        // 7,864,320
    bf16*     xpadh   = (bf16*)(base + 15728640);       // 262,144
    bf16*     xpadl   = (bf16*)(base + 15990784);       // 262,144
    float*    Dbuf    = (float*)(base + 16252928);      // 16,777,216
    float*    Pbuf    = (float*)(base + 33030144);      // 16,777,216
    bf16*     Whi     = (bf16*)(base + 49807360);       // 1,679,360
    bf16*     Wlo     = (bf16*)(base + 51486720);       // 1,679,360
    unsigned* pooledU = (unsigned*)(base + 53493760);   // 8,192
    float*    sq      = (float*)(base + 53501952);      // 16,384
    int*      flag    = (int*)(base + 53518336);        // 4

    const int Kpad[4]   = { 32, 64, 128, 256 };
    const int Os[4]     = { 64, 128, 256, 512 };
    const int Woff[5]   = { 0, 4096, 20480, 86016, 348160 };
    const int colIn[4]  = { 0, 0, 64, 192 };
    const int colOut[4] = { 0, 64, 192, 448 };

    k_prep<<<3296, 256, 0, stream>>>(Wl[0], Wl[1], Wl[2], Wl[3], W5, x,
                                     Whi, Wlo, xpadh, xpadl, sq, flag, pooledU);

    for (int l = 0; l < 4; l++) {
        int O = Os[l];
        int nTilesO = (2 * O) >> 6;
        int nBlk = 136 + 16 * nTilesO;  // even for all layers
        const bf16* Xh = (l == 0) ? xpadh : (xc_hi + colIn[l]);
        const bf16* Xl = (l == 0) ? xpadl : (xc_lo + colIn[l]);
        int ld = (l == 0) ? 32 : 960;
        size_t xstr = (l == 0) ? (size_t)NPTS * 32 : (size_t)NPTS * 960;
        k_layer_a<<<nBlk * NB, 256, 0, stream>>>(
            Xh, Xl, ld, Kpad[l], xstr, Whi + Woff[l], Wlo + Woff[l], O, sq, Dbuf, Pbuf, flag);
        k_layer_b<<<NPTS * NB / 4, 256, 0, stream>>>(
            Dbuf, Pbuf, gl[l], bl[l], O, xc_hi + colOut[l], xc_lo + colOut[l], sq, l < 3, flag);
    }
    k_conv5<<<512, 256, 0, stream>>>(xc_hi, xc_lo, Whi + Woff[4], Wlo + Woff[4],
                                     g5, b5, pooledU, flag);
    k_final<<<16, 256, 0, stream>>>(pooledU, We, d_out, flag);
}